// Round 14
// baseline (169.833 us; speedup 1.0000x reference)
//
#include <hip/hip_runtime.h>
#include <math.h>

#define DEVI static __device__ __forceinline__

typedef __attribute__((ext_vector_type(8))) short s16x8;
typedef __attribute__((ext_vector_type(4))) float f32x4;

constexpr int CH = 4096;    // edges per partition block in CSR build
constexpr int PADS = 3840;  // per-bucket pad slack: 256 dst * <=15 pad each

DEVI float bf2f(unsigned short u) {
  union { unsigned int i; float f; } v; v.i = ((unsigned int)u) << 16; return v.f;
}
DEVI unsigned short f2bf(float f) {
  union { float f; unsigned int i; } v; v.f = f;
  return (unsigned short)((v.i + 0x7fffu + ((v.i >> 16) & 1u)) >> 16);
}

// fast log1p for x in [0,1): 1+x in [1,2), no cancellation; hw log2 + scale.
DEVI float fast_log1p(float x) {
  float t = x + 1.0f;
  float l;
  asm("v_log_f32 %0, %1" : "=v"(l) : "v"(t));
  return l * 0.6931471805599453f;
}

// works for any blockDim.x
DEVI void log1p_span(const float* __restrict__ x, unsigned short* __restrict__ h0,
                     int lo, int hi, int blk, int nblk) {
  int bs = blockDim.x;
  int stride = nblk * bs;
  for (int i = lo + blk * bs + threadIdx.x; i < hi; i += stride) {
    float4 v = ((const float4*)x)[i];
    ushort4 o;
    o.x = f2bf(fast_log1p(v.x)); o.y = f2bf(fast_log1p(v.y));
    o.z = f2bf(fast_log1p(v.z)); o.w = f2bf(fast_log1p(v.w));
    ((ushort4*)h0)[i] = o;
  }
}

// ---------------- per-wave mean-aggregation body (wave handles one dst node) ----------------
template <int UL, int PL>
DEVI void gstep(const unsigned short* __restrict__ hsrc, const int* __restrict__ ss,
                unsigned base, int half, int c32, float* fa) {
  constexpr int F = PL * 32;
  int sv[UL];
#pragma unroll
  for (int u = 0; u < UL; ++u) sv[u] = ss[base + 2 * u + half];
  if constexpr (PL == 4) {
    uint2 v[UL];
#pragma unroll
    for (int u = 0; u < UL; ++u) v[u] = *(const uint2*)&hsrc[(size_t)sv[u] * F + c32 * 4];
#pragma unroll
    for (int u = 0; u < UL; ++u) {
      fa[0] += bf2f((unsigned short)(v[u].x & 0xffffu));
      fa[1] += bf2f((unsigned short)(v[u].x >> 16));
      fa[2] += bf2f((unsigned short)(v[u].y & 0xffffu));
      fa[3] += bf2f((unsigned short)(v[u].y >> 16));
    }
  } else {
    uint4 v[UL];
#pragma unroll
    for (int u = 0; u < UL; ++u) v[u] = *(const uint4*)&hsrc[(size_t)sv[u] * F + c32 * 8];
#pragma unroll
    for (int u = 0; u < UL; ++u) {
      fa[0] += bf2f((unsigned short)(v[u].x & 0xffffu));
      fa[1] += bf2f((unsigned short)(v[u].x >> 16));
      fa[2] += bf2f((unsigned short)(v[u].y & 0xffffu));
      fa[3] += bf2f((unsigned short)(v[u].y >> 16));
      fa[4] += bf2f((unsigned short)(v[u].z & 0xffffu));
      fa[5] += bf2f((unsigned short)(v[u].z >> 16));
      fa[6] += bf2f((unsigned short)(v[u].w & 0xffffu));
      fa[7] += bf2f((unsigned short)(v[u].w >> 16));
    }
  }
}

template <int F>  // 128 or 256
DEVI void agg_wave(const unsigned short* __restrict__ hsrc, const int* __restrict__ ss,
                   const unsigned* __restrict__ off, const unsigned* __restrict__ cnt,
                   unsigned short* __restrict__ agg, int d, int l) {
  constexpr int PL = F / 32;
  int half = l >> 5, c32 = l & 31;
  unsigned o = off[d];
  int n = (int)cnt[d];
  int npad = (n + 15) & ~15;  // segments pre-padded with sentinel (zero-row) edges
  float fa[PL];
#pragma unroll
  for (int f = 0; f < PL; ++f) fa[f] = 0.f;

  for (int i = 0; i < npad; i += 16) gstep<8, PL>(hsrc, ss, o + i, half, c32, fa);

#pragma unroll
  for (int f = 0; f < PL; ++f) fa[f] += __shfl_xor(fa[f], 32, 64);

  float inv = 1.0f / (float)((n > 0) ? n : 1);
  if (l < 32) {
    if constexpr (PL == 4) {
      uint2 ov;
      ov.x = (unsigned)f2bf(fa[0] * inv) | ((unsigned)f2bf(fa[1] * inv) << 16);
      ov.y = (unsigned)f2bf(fa[2] * inv) | ((unsigned)f2bf(fa[3] * inv) << 16);
      *(uint2*)&agg[(size_t)d * F + c32 * 4] = ov;
    } else {
      uint4 ov;
      ov.x = (unsigned)f2bf(fa[0] * inv) | ((unsigned)f2bf(fa[1] * inv) << 16);
      ov.y = (unsigned)f2bf(fa[2] * inv) | ((unsigned)f2bf(fa[3] * inv) << 16);
      ov.z = (unsigned)f2bf(fa[4] * inv) | ((unsigned)f2bf(fa[5] * inv) << 16);
      ov.w = (unsigned)f2bf(fa[6] * inv) | ((unsigned)f2bf(fa[7] * inv) << 16);
      *(uint4*)&agg[(size_t)d * F + c32 * 8] = ov;
    }
  }
}

// ---------------- front: hist | weight prep + sentinel zeroing | log1p span ----------------
__global__ __launch_bounds__(256) void front_k(const int* __restrict__ dst0, int E0,
                                               const int* __restrict__ dst1, int E1,
                                               unsigned* __restrict__ gh, int B0, int B1,
                                               const float* __restrict__ Ws0, const float* __restrict__ Wn0,
                                               const float* __restrict__ Ws1, const float* __restrict__ Wn1,
                                               const float* __restrict__ Wmu, const float* __restrict__ Wvar,
                                               unsigned short* __restrict__ T0s, unsigned short* __restrict__ T0n,
                                               unsigned short* __restrict__ T1s, unsigned short* __restrict__ T1n,
                                               unsigned short* __restrict__ Thead,
                                               unsigned short* __restrict__ h1z, int N0, int N1,
                                               const float* __restrict__ x, unsigned short* __restrict__ h0,
                                               int lo, int hi, int LA) {
  __shared__ unsigned h[256];
  int b = blockIdx.x;
  int t = threadIdx.x;
  int BH = B0 + B1;
  if (b < BH) {
    bool L1 = b >= B0;
    const int* dst = L1 ? dst1 : dst0;
    int E = L1 ? E1 : E0;
    int base = L1 ? b - B0 : b;
    unsigned* out = L1 ? gh + 256 * B0 : gh;
    int B = L1 ? B1 : B0;
    h[t] = 0;
    __syncthreads();
    int e0 = base * CH, eend = min(e0 + CH, E);
    for (int i = e0 + t; i < eend; i += 256) atomicAdd(&h[((unsigned)dst[i]) >> 8], 1u);
    __syncthreads();
    out[t * B + base] = h[t];
  } else if (b < BH + 256) {
    if (b == BH) {  // zero the sentinel rows (gather targets for pad edges)
      if (t < 64) ((unsigned*)h0)[(size_t)N0 * 64 + t] = 0u;    // h0 row N0 (128 bf16)
      if (t < 128) ((unsigned*)h1z)[(size_t)N1 * 128 + t] = 0u; // h1 row N1 (256 bf16)
    }
    int i = (b - BH) * 256 + t;
    if (i < 32768) {  // [256][128]
      int hh = i >> 7, k = i & 127;
      T0s[i] = f2bf(Ws0[k * 256 + hh]);
      T0n[i] = f2bf(Wn0[k * 256 + hh]);
    }
    if (i < 65536) {  // [256][256]
      int hh = i >> 8, k = i & 255;
      T1s[i] = f2bf(Ws1[k * 256 + hh]);
      T1n[i] = f2bf(Wn1[k * 256 + hh]);
    }
    if (i < 16384) {  // Thead[64][256]
      int c = i >> 8, k = i & 255;
      Thead[i] = f2bf(c < 32 ? Wmu[k * 32 + c] : Wvar[k * 32 + (c - 32)]);
    }
  } else {
    log1p_span(x, h0, lo, hi, b - BH - 256, LA);
  }
}

// ---------------- scan: per-chunk sums | log1p span ----------------
__global__ __launch_bounds__(256) void scan_sums_k(const unsigned* __restrict__ a, int NB,
                                                   unsigned* __restrict__ part,
                                                   const float* __restrict__ x, unsigned short* __restrict__ h0,
                                                   int lo, int hi, int LB) {
  __shared__ unsigned sm[256];
  int b = blockIdx.x, t = threadIdx.x;
  if (b >= NB) { log1p_span(x, h0, lo, hi, b - NB, LB); return; }
  sm[t] = a[b * 256 + t];
  __syncthreads();
  for (int o = 128; o > 0; o >>= 1) {
    if (t < o) sm[t] += sm[t + o];
    __syncthreads();
  }
  if (t == 0) part[b] = sm[0];
}

// ---------------- scan: self-scanned partials + chunk exclusive scan + write | log1p span ----------------
__global__ __launch_bounds__(256) void scan_write_k(unsigned* __restrict__ a, int NB,
                                                    const unsigned* __restrict__ part,
                                                    const float* __restrict__ x, unsigned short* __restrict__ h0,
                                                    int lo, int hi, int LC) {
  __shared__ unsigned sm[256];
  int b = blockIdx.x, t = threadIdx.x;
  if (b >= NB) { log1p_span(x, h0, lo, hi, b - NB, LC); return; }
  unsigned pv = (t < NB) ? part[t] : 0u;
  sm[t] = pv;
  __syncthreads();
  for (int o = 1; o < 256; o <<= 1) {
    unsigned xv = (t >= o) ? sm[t - o] : 0u;
    __syncthreads();
    sm[t] += xv;
    __syncthreads();
  }
  unsigned pb = (b == 0) ? 0u : sm[b - 1];
  __syncthreads();
  unsigned v = a[b * 256 + t];
  sm[t] = v;
  __syncthreads();
  for (int o = 1; o < 256; o <<= 1) {
    unsigned xv = (t >= o) ? sm[t - o] : 0u;
    __syncthreads();
    sm[t] += xv;
    __syncthreads();
  }
  a[b * 256 + t] = pb + sm[t] - v;
}

// ---------------- scatter: 1024-thread blocks (+ final log1p span) ----------------
__global__ __launch_bounds__(1024) void scatter2_k(const int* __restrict__ src0, const int* __restrict__ dst0, int E0,
                                                   const int* __restrict__ src1, const int* __restrict__ dst1, int E1,
                                                   const unsigned* __restrict__ gh, int B0, int B1,
                                                   uint2* __restrict__ tmp,
                                                   const float* __restrict__ x, unsigned short* __restrict__ h0,
                                                   int lo, int hi, int LS) {
  __shared__ unsigned cur[256];
  int b = blockIdx.x;
  int NB = B0 + B1;
  if (b >= NB) { log1p_span(x, h0, lo, hi, b - NB, LS); return; }
  bool L1 = b >= B0;
  const int* dst = L1 ? dst1 : dst0;
  const int* src = L1 ? src1 : src0;
  int E = L1 ? E1 : E0;
  int base = L1 ? b - B0 : b;
  const unsigned* g = L1 ? gh + 256 * B0 : gh;
  int B = L1 ? B1 : B0;
  int t = threadIdx.x;
  if (t < 256) cur[t] = g[t * B + base];
  __syncthreads();
  int e0 = base * CH, eend = min(e0 + CH, E);
  for (int i = e0 + t; i < eend; i += 1024) {
    int d = dst[i];
    unsigned p = atomicAdd(&cur[((unsigned)d) >> 8], 1u);
    tmp[p] = make_uint2((unsigned)d, (unsigned)src[i]);
  }
}

// ---------------- finalize buckets [qlo, qlo+nfin) | co-scheduled agg0 (16 dst/block) ----------------
__global__ __launch_bounds__(1024) void finagg_k(const uint2* __restrict__ tmp, const unsigned* __restrict__ gh,
                                                 int B0, int B1, int N1, int N2,
                                                 unsigned* __restrict__ off, unsigned* __restrict__ cnt,
                                                 int* __restrict__ ss, int QB0, int QB1,
                                                 int sent0, int sent1, int qlo, int nfin,
                                                 const unsigned short* __restrict__ h0agg,
                                                 unsigned short* __restrict__ agg0, int aggd0, int aggM) {
  __shared__ unsigned h[256];
  __shared__ unsigned sm[256];
  __shared__ unsigned co[256];
  int b = blockIdx.x;
  int t = threadIdx.x;
  if (b >= nfin) {  // agg0 co-schedule: 16 waves -> 16 dst nodes
    int d = aggd0 + (b - nfin) * 16 + (t >> 6);
    if (d < aggM) agg_wave<128>(h0agg, ss, off, cnt, agg0, d, t & 63);
    return;
  }
  int q = qlo + b;
  bool L1 = q >= QB0;
  int Nd = L1 ? N2 : N1;
  int qb = L1 ? q - QB0 : q;
  const unsigned* g = L1 ? gh + 256 * B0 : gh;
  int B = L1 ? B1 : B0;
  unsigned bstart = g[qb * B];
  unsigned bend = g[(qb + 1) * B];
  unsigned nbk = bend - bstart;
  unsigned pbase = bstart + (unsigned)q * PADS;

  if (t < 256) h[t] = 0;
  __syncthreads();
  for (unsigned i = t; i < nbk; i += 1024) atomicAdd(&h[tmp[bstart + i].x & 255u], 1u);
  __syncthreads();
  unsigned v = 0, vpad = 0;
  if (t < 256) {
    v = h[t];
    vpad = (v + 15u) & ~15u;
    sm[t] = vpad;
  }
  __syncthreads();
  for (int o = 1; o < 256; o <<= 1) {
    unsigned xv = 0;
    if (t < 256 && t >= o) xv = sm[t - o];
    __syncthreads();
    if (t < 256) sm[t] += xv;
    __syncthreads();
  }
  if (t < 256) {
    unsigned myoff = pbase + sm[t] - vpad;
    int dl = qb * 256 + t;
    if (dl < Nd) {
      int dg = (L1 ? N1 : 0) + dl;
      off[dg] = myoff;
      cnt[dg] = v;  // TRUE degree for the mean
    }
    co[t] = myoff;
    int sent = L1 ? sent1 : sent0;
    for (unsigned j = v; j < vpad; ++j) ss[myoff + j] = sent;
  }
  __syncthreads();
  for (unsigned i = t; i < nbk; i += 1024) {
    uint2 e = tmp[bstart + i];
    unsigned p = atomicAdd(&co[e.x & 255u], 1u);
    ss[p] = (int)e.y;
  }
}

// ---------------- standalone aggregate (agg1): 4 dst per 256-thr block ----------------
template <int F>
__global__ __launch_bounds__(256) void aggregate_k(const unsigned short* __restrict__ hsrc,
                                                   const int* __restrict__ ss,
                                                   const unsigned* __restrict__ off,
                                                   const unsigned* __restrict__ cnt,
                                                   unsigned short* __restrict__ agg, int M) {
  int d = blockIdx.x * 4 + (threadIdx.x >> 6);
  if (d >= M) return;
  agg_wave<F>(hsrc, ss, off, cnt, agg, d, threadIdx.x & 63);
}

// ---------------- staged layer GEMM (tiles [tile0, tile0+ngemm)) | co-scheduled agg0 (8 dst/block) ----------------
template <int KD, bool HEAD>
__global__ __launch_bounds__(512) void layer_gemm_k(const unsigned short* __restrict__ Aself,
                                                    const unsigned short* __restrict__ Aagg,
                                                    const unsigned short* __restrict__ WtS,
                                                    const unsigned short* __restrict__ WtN,
                                                    const float* __restrict__ bias,
                                                    unsigned short* __restrict__ Hout,        // !HEAD
                                                    const unsigned short* __restrict__ Thead, // [64][256], HEAD
                                                    const float* __restrict__ bmu, const float* __restrict__ bvar,
                                                    float* __restrict__ outp, int M,
                                                    int tile0, int ngemm,
                                                    const int* __restrict__ ss,
                                                    const unsigned* __restrict__ off,
                                                    const unsigned* __restrict__ cnt, int aggd0) {
  __shared__ unsigned short At[128][40];
  __shared__ unsigned short Bt[256][40];
  __shared__ float rowsq[4][128];
  __shared__ float rowtot[128];
  __shared__ unsigned short h2t[HEAD ? 128 : 1][HEAD ? 264 : 1];

  int tid = threadIdx.x;
  if (blockIdx.x >= ngemm) {  // agg0 co-schedule: 8 waves -> 8 dst nodes
    int d = aggd0 + (blockIdx.x - ngemm) * 8 + (tid >> 6);
    if (d < M) agg_wave<KD>(Aself, ss, off, cnt, (unsigned short*)Aagg, d, tid & 63);
    return;
  }
  int w = tid >> 6, l = tid & 63;
  int wr = w >> 2, wc = w & 3;
  int m0 = (tile0 + blockIdx.x) * 128;

  f32x4 acc[4][4];
#pragma unroll
  for (int rt = 0; rt < 4; ++rt)
#pragma unroll
    for (int ct = 0; ct < 4; ++ct) acc[rt][ct] = (f32x4)(0.f);

  for (int s = 0; s < 2; ++s) {
    const unsigned short* A = s ? Aagg : Aself;
    const unsigned short* Wt = s ? WtN : WtS;
    for (int k0 = 0; k0 < KD; k0 += 32) {
      {
        int r = tid >> 2, c8 = (tid & 3) << 3;
        int gr = m0 + r;
        uint4 v = make_uint4(0, 0, 0, 0);
        if (gr < M) v = *(const uint4*)&A[(size_t)gr * KD + k0 + c8];
        *(uint4*)&At[r][c8] = v;
      }
#pragma unroll
      for (int rr = 0; rr < 2; ++rr) {
        int r = (tid >> 2) + (rr << 7), c8 = (tid & 3) << 3;
        uint4 v = *(const uint4*)&Wt[(size_t)r * KD + k0 + c8];
        *(uint4*)&Bt[r][c8] = v;
      }
      __syncthreads();
      s16x8 a[4], b[4];
#pragma unroll
      for (int rt = 0; rt < 4; ++rt) a[rt] = *(const s16x8*)&At[wr * 64 + rt * 16 + (l & 15)][(l >> 4) * 8];
#pragma unroll
      for (int ct = 0; ct < 4; ++ct) b[ct] = *(const s16x8*)&Bt[wc * 64 + ct * 16 + (l & 15)][(l >> 4) * 8];
#pragma unroll
      for (int rt = 0; rt < 4; ++rt)
#pragma unroll
        for (int ct = 0; ct < 4; ++ct)
          acc[rt][ct] = __builtin_amdgcn_mfma_f32_16x16x32_bf16(a[rt], b[ct], acc[rt][ct], 0, 0, 0);
      __syncthreads();
    }
  }

  float pr[4][4];
#pragma unroll
  for (int rt = 0; rt < 4; ++rt)
#pragma unroll
    for (int j = 0; j < 4; ++j) pr[rt][j] = 0.f;
#pragma unroll
  for (int rt = 0; rt < 4; ++rt)
#pragma unroll
    for (int ct = 0; ct < 4; ++ct) {
      int c = wc * 64 + ct * 16 + (l & 15);
      float bv = bias[c];
#pragma unroll
      for (int j = 0; j < 4; ++j) {
        float vv = acc[rt][ct][j] + bv;
        vv = fmaxf(vv, 0.f);
        acc[rt][ct][j] = vv;
        pr[rt][j] += vv * vv;
      }
    }
#pragma unroll
  for (int rt = 0; rt < 4; ++rt)
#pragma unroll
    for (int j = 0; j < 4; ++j) {
      float p = pr[rt][j];
      for (int m = 1; m < 16; m <<= 1) p += __shfl_xor(p, m, 64);
      pr[rt][j] = p;
    }
  if ((l & 15) == 0) {
#pragma unroll
    for (int rt = 0; rt < 4; ++rt)
#pragma unroll
      for (int j = 0; j < 4; ++j) rowsq[wc][wr * 64 + rt * 16 + (l >> 4) * 4 + j] = pr[rt][j];
  }
  __syncthreads();
  if (tid < 128) rowtot[tid] = rowsq[0][tid] + rowsq[1][tid] + rowsq[2][tid] + rowsq[3][tid];
  __syncthreads();

  if constexpr (!HEAD) {
#pragma unroll
    for (int rt = 0; rt < 4; ++rt) {
      int rbase = wr * 64 + rt * 16 + (l >> 4) * 4;
#pragma unroll
      for (int j = 0; j < 4; ++j) {
        int r = rbase + j;
        int gr = m0 + r;
        if (gr < M) {
          float inv = 1.0f / fmaxf(sqrtf(rowtot[r]), 1e-12f);
#pragma unroll
          for (int ct = 0; ct < 4; ++ct) {
            int c = wc * 64 + ct * 16 + (l & 15);
            Hout[(size_t)gr * 256 + c] = f2bf(acc[rt][ct][j] * inv);
          }
        }
      }
    }
  } else {
#pragma unroll
    for (int rt = 0; rt < 4; ++rt) {
      int rbase = wr * 64 + rt * 16 + (l >> 4) * 4;
#pragma unroll
      for (int j = 0; j < 4; ++j) {
        int r = rbase + j;
        float inv = 1.0f / fmaxf(sqrtf(rowtot[r]), 1e-12f);
#pragma unroll
        for (int ct = 0; ct < 4; ++ct) {
          int c = wc * 64 + ct * 16 + (l & 15);
          h2t[r][c] = f2bf(acc[rt][ct][j] * inv);
        }
      }
    }
    __syncthreads();

    const int arow = wr * 64 + (l & 15);
    const int kk = (l >> 4) * 8;
    f32x4 hacc[4];
#pragma unroll
    for (int rt = 0; rt < 4; ++rt) hacc[rt] = (f32x4)(0.f);
#pragma unroll
    for (int k0 = 0; k0 < 256; k0 += 32) {
      s16x8 ha[4];
#pragma unroll
      for (int rt = 0; rt < 4; ++rt) ha[rt] = *(const s16x8*)&h2t[arow + rt * 16][k0 + kk];
      s16x8 hb = *(const s16x8*)&Thead[(size_t)(wc * 16 + (l & 15)) * 256 + k0 + kk];
#pragma unroll
      for (int rt = 0; rt < 4; ++rt)
        hacc[rt] = __builtin_amdgcn_mfma_f32_16x16x32_bf16(ha[rt], hb, hacc[rt], 0, 0, 0);
    }
    const int c = wc * 16 + (l & 15);
    const float hbias = (c < 32) ? bmu[c] : bvar[c - 32];
#pragma unroll
    for (int rt = 0; rt < 4; ++rt)
#pragma unroll
      for (int j = 0; j < 4; ++j) {
        int gr = m0 + wr * 64 + rt * 16 + (l >> 4) * 4 + j;
        if (gr < M) {
          float val = hacc[rt][j] + hbias;
          if (c < 32)
            outp[(size_t)gr * 32 + c] = val;
          else
            outp[(size_t)M * 32 + (size_t)gr * 32 + (c - 32)] = expf(val) + 1e-6f;
        }
      }
  }
}

extern "C" void kernel_launch(void* const* d_in, const int* in_sizes, int n_in,
                              void* d_out, int out_size, void* d_ws, size_t ws_size,
                              hipStream_t stream) {
  const float* x    = (const float*)d_in[0];
  const float* Ws0  = (const float*)d_in[1];
  const float* Wn0  = (const float*)d_in[2];
  const float* b0   = (const float*)d_in[3];
  const float* Ws1  = (const float*)d_in[4];
  const float* Wn1  = (const float*)d_in[5];
  const float* b1   = (const float*)d_in[6];
  const float* Wmu  = (const float*)d_in[7];
  const float* bmu  = (const float*)d_in[8];
  const float* Wvar = (const float*)d_in[9];
  const float* bvar = (const float*)d_in[10];
  const int* src0   = (const int*)d_in[11];
  const int* dst0   = (const int*)d_in[12];
  const int* src1   = (const int*)d_in[13];
  const int* dst1   = (const int*)d_in[14];

  const int N0 = in_sizes[0] / 128;  // 200000
  const int E0 = in_sizes[11];       // 800000
  const int E1 = in_sizes[13];       // 160000
  const int N1 = 50000, N2 = 10000;  // n_dst0 / n_dst1 (fixed problem shape)
  const int M = N1 + N2;

  char* ws = (char*)d_ws;
  size_t o = 0;
  auto take = [&](size_t b) -> char* {
    size_t cur = (o + 255) & ~(size_t)255;
    o = cur + b;
    return ws + cur;
  };
  unsigned short* h0    = (unsigned short*)take((size_t)(N0 + 1) * 128 * 2);  // +1 sentinel zero row
  unsigned short* agg0  = (unsigned short*)take((size_t)N1 * 128 * 2);
  unsigned short* h1    = (unsigned short*)take((size_t)(N1 + 1) * 256 * 2);  // +1 sentinel zero row
  unsigned short* agg1  = (unsigned short*)take((size_t)N2 * 256 * 2);
  unsigned short* T0s   = (unsigned short*)take(256 * 128 * 2);
  unsigned short* T0n   = (unsigned short*)take(256 * 128 * 2);
  unsigned short* T1s   = (unsigned short*)take(256 * 256 * 2);
  unsigned short* T1n   = (unsigned short*)take(256 * 256 * 2);
  unsigned short* Thead = (unsigned short*)take(64 * 256 * 2);

  int B0 = (E0 + CH - 1) / CH;   // 196
  int B1 = (E1 + CH - 1) / CH;   // 40
  int NB = B0 + B1;              // 236
  int G  = 256 * NB;
  int QB0 = (N1 + 255) / 256;    // 196
  int QB1 = (N2 + 255) / 256;    // 40
  int QF  = QB0 + QB1;           // 236

  unsigned* gh   = (unsigned*)take((size_t)G * 4);
  unsigned* off  = (unsigned*)take((size_t)M * 4);
  unsigned* cnt  = (unsigned*)take((size_t)M * 4);
  unsigned* part = (unsigned*)take(256 * 4);
  uint2* tmp = (uint2*)take((size_t)(E0 + E1) * 8);
  int* ss = (int*)take(((size_t)(E0 + E1) + (size_t)QF * PADS) * 4);  // padded CSR buffer
  (void)ws_size;

  const int n4 = N0 * 128 / 4;  // 6.4M float4
  // log1p spans: 20% | 15% | 15% | 50% — h0 complete after scatter
  const int c1 = n4 * 20 / 100, c2 = n4 * 35 / 100, c3 = n4 * 50 / 100;
  const int LA = 768, LBs = 768, LC = 768, LS = 384;

  // pipeline split points (layer 0)
  const int QH = 118;            // finalize buckets half (layer-0 rows [0, 30208))
  const int RH = QH * 256;       // 30208 agg0 rows ready after stage A
  const int TH = RH / 128;       // 236 gemm0 tiles over those rows
  const int T0cnt = (N1 + 127) / 128;  // 391 total layer-0 tiles

  // 1) front: hist + weight prep + sentinels + log1p[0,c1)
  front_k<<<NB + 256 + LA, 256, 0, stream>>>(dst0, E0, dst1, E1, gh, B0, B1,
                                             Ws0, Wn0, Ws1, Wn1, Wmu, Wvar,
                                             T0s, T0n, T1s, T1n, Thead,
                                             h1, N0, N1,
                                             x, h0, 0, c1, LA);

  // 2) scan sums + log1p[c1,c2) ; scan write + log1p[c2,c3)
  scan_sums_k<<<NB + LBs, 256, 0, stream>>>(gh, NB, part, x, h0, c1, c2, LBs);
  scan_write_k<<<NB + LC, 256, 0, stream>>>(gh, NB, part, x, h0, c2, c3, LC);

  // 3) scatter + log1p[c3,n4) — h0 fully written after this
  scatter2_k<<<NB + LS, 1024, 0, stream>>>(src0, dst0, E0, src1, dst1, E1, gh, B0, B1, tmp,
                                           x, h0, c3, n4, LS);

  // 4) pipelined finalize -> agg0 -> gemm0
  //    A: finalize buckets [0, QH)
  finagg_k<<<QH, 1024, 0, stream>>>(tmp, gh, B0, B1, N1, N2, off, cnt, ss, QB0, QB1,
                                    N0, N1, 0, QH, h0, agg0, 0, 0);
  //    B: finalize buckets [QH, QF) || agg0 rows [0, RH)
  int aggAblk = RH / 16;  // 1888
  finagg_k<<<(QF - QH) + aggAblk, 1024, 0, stream>>>(tmp, gh, B0, B1, N1, N2, off, cnt, ss, QB0, QB1,
                                                     N0, N1, QH, QF - QH, h0, agg0, 0, RH);
  //    C: agg0 rows [RH, N1) || gemm0 tiles [0, TH)
  int aggBblk = (N1 - RH + 7) / 8;  // 2474
  layer_gemm_k<128, false><<<TH + aggBblk, 512, 0, stream>>>(h0, agg0, T0s, T0n, b0,
                                                             h1, nullptr, nullptr, nullptr, nullptr, N1,
                                                             0, TH, ss, off, cnt, RH);
  //    D: gemm0 tiles [TH, T0cnt)
  layer_gemm_k<128, false><<<T0cnt - TH, 512, 0, stream>>>(h0, agg0, T0s, T0n, b0,
                                                           h1, nullptr, nullptr, nullptr, nullptr, N1,
                                                           TH, T0cnt - TH, nullptr, nullptr, nullptr, 0);

  // 5) layer 1: aggregate then GEMM + fused head -> out
  aggregate_k<256><<<(N2 + 3) / 4, 256, 0, stream>>>(h1, ss, off + N1, cnt + N1, agg1, N2);
  layer_gemm_k<256, true><<<(N2 + 127) / 128, 512, 0, stream>>>(h1, agg1, T1s, T1n, b1,
                                                                nullptr, Thead, bmu, bvar, (float*)d_out, N2,
                                                                0, (N2 + 127) / 128, nullptr, nullptr, nullptr, 0);
}

// Round 15
// 149.902 us; speedup vs baseline: 1.1330x; 1.1330x over previous
//
#include <hip/hip_runtime.h>
#include <math.h>

#define DEVI static __device__ __forceinline__

typedef __attribute__((ext_vector_type(8))) short s16x8;
typedef __attribute__((ext_vector_type(4))) float f32x4;

constexpr int CH = 4096;    // edges per partition block in CSR build
constexpr int PADS = 3840;  // per-bucket pad slack: 256 dst * <=15 pad each

DEVI float bf2f(unsigned short u) {
  union { unsigned int i; float f; } v; v.i = ((unsigned int)u) << 16; return v.f;
}
DEVI unsigned short f2bf(float f) {
  union { float f; unsigned int i; } v; v.f = f;
  return (unsigned short)((v.i + 0x7fffu + ((v.i >> 16) & 1u)) >> 16);
}

// fast log1p for x in [0,1): 1+x in [1,2), no cancellation; hw log2 + scale.
DEVI float fast_log1p(float x) {
  float t = x + 1.0f;
  float l;
  asm("v_log_f32 %0, %1" : "=v"(l) : "v"(t));
  return l * 0.6931471805599453f;
}

// works for any blockDim.x (256 or 1024 callers)
DEVI void log1p_span(const float* __restrict__ x, unsigned short* __restrict__ h0,
                     int lo, int hi, int blk, int nblk) {
  int bs = blockDim.x;
  int stride = nblk * bs;
  for (int i = lo + blk * bs + threadIdx.x; i < hi; i += stride) {
    float4 v = ((const float4*)x)[i];
    ushort4 o;
    o.x = f2bf(fast_log1p(v.x)); o.y = f2bf(fast_log1p(v.y));
    o.z = f2bf(fast_log1p(v.z)); o.w = f2bf(fast_log1p(v.w));
    ((ushort4*)h0)[i] = o;
  }
}

// ---------------- front: hist (CSR level-1a) | weight prep + sentinel zeroing | log1p span ----------------
__global__ __launch_bounds__(256) void front_k(const int* __restrict__ dst0, int E0,
                                               const int* __restrict__ dst1, int E1,
                                               unsigned* __restrict__ gh, int B0, int B1,
                                               const float* __restrict__ Ws0, const float* __restrict__ Wn0,
                                               const float* __restrict__ Ws1, const float* __restrict__ Wn1,
                                               const float* __restrict__ Wmu, const float* __restrict__ Wvar,
                                               unsigned short* __restrict__ T0s, unsigned short* __restrict__ T0n,
                                               unsigned short* __restrict__ T1s, unsigned short* __restrict__ T1n,
                                               unsigned short* __restrict__ Thead,
                                               unsigned short* __restrict__ h1z, int N0, int N1,
                                               const float* __restrict__ x, unsigned short* __restrict__ h0,
                                               int lo, int hi, int LA) {
  __shared__ unsigned h[256];
  int b = blockIdx.x;
  int t = threadIdx.x;
  int BH = B0 + B1;
  if (b < BH) {
    bool L1 = b >= B0;
    const int* dst = L1 ? dst1 : dst0;
    int E = L1 ? E1 : E0;
    int base = L1 ? b - B0 : b;
    unsigned* out = L1 ? gh + 256 * B0 : gh;
    int B = L1 ? B1 : B0;
    h[t] = 0;
    __syncthreads();
    int e0 = base * CH, eend = min(e0 + CH, E);
    for (int i = e0 + t; i < eend; i += 256) atomicAdd(&h[((unsigned)dst[i]) >> 8], 1u);
    __syncthreads();
    out[t * B + base] = h[t];
  } else if (b < BH + 256) {
    if (b == BH) {  // zero the sentinel rows (gather targets for pad edges)
      if (t < 64) ((unsigned*)h0)[(size_t)N0 * 64 + t] = 0u;    // h0 row N0 (128 bf16)
      if (t < 128) ((unsigned*)h1z)[(size_t)N1 * 128 + t] = 0u; // h1 row N1 (256 bf16)
    }
    int i = (b - BH) * 256 + t;
    if (i < 32768) {  // [256][128]
      int hh = i >> 7, k = i & 127;
      T0s[i] = f2bf(Ws0[k * 256 + hh]);
      T0n[i] = f2bf(Wn0[k * 256 + hh]);
    }
    if (i < 65536) {  // [256][256]
      int hh = i >> 8, k = i & 255;
      T1s[i] = f2bf(Ws1[k * 256 + hh]);
      T1n[i] = f2bf(Wn1[k * 256 + hh]);
    }
    if (i < 16384) {  // Thead[64][256]
      int c = i >> 8, k = i & 255;
      Thead[i] = f2bf(c < 32 ? Wmu[k * 32 + c] : Wvar[k * 32 + (c - 32)]);
    }
  } else {
    log1p_span(x, h0, lo, hi, b - BH - 256, LA);
  }
}

// ---------------- scan: per-chunk sums | log1p span ----------------
__global__ __launch_bounds__(256) void scan_sums_k(const unsigned* __restrict__ a, int NB,
                                                   unsigned* __restrict__ part,
                                                   const float* __restrict__ x, unsigned short* __restrict__ h0,
                                                   int lo, int hi, int LB) {
  __shared__ unsigned sm[256];
  int b = blockIdx.x, t = threadIdx.x;
  if (b >= NB) { log1p_span(x, h0, lo, hi, b - NB, LB); return; }
  sm[t] = a[b * 256 + t];
  __syncthreads();
  for (int o = 128; o > 0; o >>= 1) {
    if (t < o) sm[t] += sm[t + o];
    __syncthreads();
  }
  if (t == 0) part[b] = sm[0];
}

// ---------------- scan: self-service partial scan + chunk exclusive scan + write | log1p span ----------------
__global__ __launch_bounds__(256) void scan_write_k(unsigned* __restrict__ a, int NB,
                                                    const unsigned* __restrict__ part,
                                                    const float* __restrict__ x, unsigned short* __restrict__ h0,
                                                    int lo, int hi, int LC) {
  __shared__ unsigned sm[256];
  int b = blockIdx.x, t = threadIdx.x;
  if (b >= NB) { log1p_span(x, h0, lo, hi, b - NB, LC); return; }
  unsigned pv = (t < NB) ? part[t] : 0u;
  sm[t] = pv;
  __syncthreads();
  for (int o = 1; o < 256; o <<= 1) {
    unsigned xv = (t >= o) ? sm[t - o] : 0u;
    __syncthreads();
    sm[t] += xv;
    __syncthreads();
  }
  unsigned pb = (b == 0) ? 0u : sm[b - 1];
  __syncthreads();
  unsigned v = a[b * 256 + t];
  sm[t] = v;
  __syncthreads();
  for (int o = 1; o < 256; o <<= 1) {
    unsigned xv = (t >= o) ? sm[t - o] : 0u;
    __syncthreads();
    sm[t] += xv;
    __syncthreads();
  }
  a[b * 256 + t] = pb + sm[t] - v;
}

// ---------------- scatter: 1024-thread blocks (16 waves/CU, 4x edge TLP) (+ log1p span) ----------------
__global__ __launch_bounds__(1024) void scatter2_k(const int* __restrict__ src0, const int* __restrict__ dst0, int E0,
                                                   const int* __restrict__ src1, const int* __restrict__ dst1, int E1,
                                                   const unsigned* __restrict__ gh, int B0, int B1,
                                                   uint2* __restrict__ tmp,
                                                   const float* __restrict__ x, unsigned short* __restrict__ h0,
                                                   int lo, int hi, int LS) {
  __shared__ unsigned cur[256];
  int b = blockIdx.x;
  int NB = B0 + B1;
  if (b >= NB) { log1p_span(x, h0, lo, hi, b - NB, LS); return; }
  bool L1 = b >= B0;
  const int* dst = L1 ? dst1 : dst0;
  const int* src = L1 ? src1 : src0;
  int E = L1 ? E1 : E0;
  int base = L1 ? b - B0 : b;
  const unsigned* g = L1 ? gh + 256 * B0 : gh;
  int B = L1 ? B1 : B0;
  int t = threadIdx.x;
  if (t < 256) cur[t] = g[t * B + base];
  __syncthreads();
  int e0 = base * CH, eend = min(e0 + CH, E);
  for (int i = e0 + t; i < eend; i += 1024) {
    int d = dst[i];
    unsigned p = atomicAdd(&cur[((unsigned)d) >> 8], 1u);
    tmp[p] = make_uint2((unsigned)d, (unsigned)src[i]);
  }
}

// ---------------- finalize: 1024-thread blocks, padded segments + sentinel fill (+ log1p span) ----------------
__global__ __launch_bounds__(1024) void finalize_k(const uint2* __restrict__ tmp, const unsigned* __restrict__ gh,
                                                   int B0, int B1, int N1, int N2,
                                                   unsigned* __restrict__ off, unsigned* __restrict__ cnt,
                                                   int* __restrict__ ss, int QB0, int QB1,
                                                   int sent0, int sent1,
                                                   const float* __restrict__ x, unsigned short* __restrict__ h0,
                                                   int lo, int hi, int LF) {
  __shared__ unsigned h[256];
  __shared__ unsigned sm[256];
  __shared__ unsigned co[256];
  int q = blockIdx.x;
  int QF = QB0 + QB1;
  if (q >= QF) { log1p_span(x, h0, lo, hi, q - QF, LF); return; }
  bool L1 = q >= QB0;
  int Nd = L1 ? N2 : N1;
  int qb = L1 ? q - QB0 : q;
  const unsigned* g = L1 ? gh + 256 * B0 : gh;
  int B = L1 ? B1 : B0;
  int t = threadIdx.x;
  unsigned bstart = g[qb * B];
  unsigned bend = g[(qb + 1) * B];
  unsigned nbk = bend - bstart;
  unsigned pbase = bstart + (unsigned)q * PADS;  // per-bucket padded region start

  if (t < 256) h[t] = 0;
  __syncthreads();
  for (unsigned i = t; i < nbk; i += 1024) atomicAdd(&h[tmp[bstart + i].x & 255u], 1u);
  __syncthreads();
  unsigned v = 0, vpad = 0;
  if (t < 256) {
    v = h[t];
    vpad = (v + 15u) & ~15u;
    sm[t] = vpad;
  }
  __syncthreads();
  for (int o = 1; o < 256; o <<= 1) {
    unsigned xv = 0;
    if (t < 256 && t >= o) xv = sm[t - o];
    __syncthreads();
    if (t < 256) sm[t] += xv;
    __syncthreads();
  }
  if (t < 256) {
    unsigned myoff = pbase + sm[t] - vpad;
    int dl = qb * 256 + t;
    if (dl < Nd) {
      int dg = (L1 ? N1 : 0) + dl;
      off[dg] = myoff;
      cnt[dg] = v;  // TRUE degree for the mean
    }
    co[t] = myoff;
    // pad fill: disjoint region per dst
    int sent = L1 ? sent1 : sent0;
    for (unsigned j = v; j < vpad; ++j) ss[myoff + j] = sent;
  }
  __syncthreads();
  for (unsigned i = t; i < nbk; i += 1024) {
    uint2 e = tmp[bstart + i];
    unsigned p = atomicAdd(&co[e.x & 255u], 1u);
    ss[p] = (int)e.y;
  }
}

// ---------------- mean aggregation: wave per dst node, uniform 16-edge dual-parity batches ----------------
template <int UL, int PL>
DEVI void gstep(const unsigned short* __restrict__ hsrc, const int* __restrict__ ss,
                unsigned base, int half, int c32, float* fa) {
  constexpr int F = PL * 32;
  int sv[UL];
#pragma unroll
  for (int u = 0; u < UL; ++u) sv[u] = ss[base + 2 * u + half];
  if constexpr (PL == 4) {
    uint2 v[UL];
#pragma unroll
    for (int u = 0; u < UL; ++u) v[u] = *(const uint2*)&hsrc[(size_t)sv[u] * F + c32 * 4];
#pragma unroll
    for (int u = 0; u < UL; ++u) {
      fa[0] += bf2f((unsigned short)(v[u].x & 0xffffu));
      fa[1] += bf2f((unsigned short)(v[u].x >> 16));
      fa[2] += bf2f((unsigned short)(v[u].y & 0xffffu));
      fa[3] += bf2f((unsigned short)(v[u].y >> 16));
    }
  } else {
    uint4 v[UL];
#pragma unroll
    for (int u = 0; u < UL; ++u) v[u] = *(const uint4*)&hsrc[(size_t)sv[u] * F + c32 * 8];
#pragma unroll
    for (int u = 0; u < UL; ++u) {
      fa[0] += bf2f((unsigned short)(v[u].x & 0xffffu));
      fa[1] += bf2f((unsigned short)(v[u].x >> 16));
      fa[2] += bf2f((unsigned short)(v[u].y & 0xffffu));
      fa[3] += bf2f((unsigned short)(v[u].y >> 16));
      fa[4] += bf2f((unsigned short)(v[u].z & 0xffffu));
      fa[5] += bf2f((unsigned short)(v[u].z >> 16));
      fa[6] += bf2f((unsigned short)(v[u].w & 0xffffu));
      fa[7] += bf2f((unsigned short)(v[u].w >> 16));
    }
  }
}

template <int F>  // 128 or 256
__global__ __launch_bounds__(256) void aggregate_k(const unsigned short* __restrict__ hsrc,
                                                   const int* __restrict__ ss,
                                                   const unsigned* __restrict__ off,
                                                   const unsigned* __restrict__ cnt,
                                                   unsigned short* __restrict__ agg, int M) {
  constexpr int PL = F / 32;  // floats per lane: 4 (F=128) or 8 (F=256)
  int w = threadIdx.x >> 6, l = threadIdx.x & 63;
  int half = l >> 5, c32 = l & 31;
  int d = blockIdx.x * 4 + w;
  if (d >= M) return;
  unsigned o = off[d];
  int n = (int)cnt[d];
  int npad = (n + 15) & ~15;  // segments are pre-padded with sentinel (zero-row) edges
  float fa[PL];
#pragma unroll
  for (int f = 0; f < PL; ++f) fa[f] = 0.f;

  for (int i = 0; i < npad; i += 16) gstep<8, PL>(hsrc, ss, o + i, half, c32, fa);

#pragma unroll
  for (int f = 0; f < PL; ++f) fa[f] += __shfl_xor(fa[f], 32, 64);

  float inv = 1.0f / (float)((n > 0) ? n : 1);
  if (l < 32) {
    if constexpr (PL == 4) {
      uint2 ov;
      ov.x = (unsigned)f2bf(fa[0] * inv) | ((unsigned)f2bf(fa[1] * inv) << 16);
      ov.y = (unsigned)f2bf(fa[2] * inv) | ((unsigned)f2bf(fa[3] * inv) << 16);
      *(uint2*)&agg[(size_t)d * F + c32 * 4] = ov;
    } else {
      uint4 ov;
      ov.x = (unsigned)f2bf(fa[0] * inv) | ((unsigned)f2bf(fa[1] * inv) << 16);
      ov.y = (unsigned)f2bf(fa[2] * inv) | ((unsigned)f2bf(fa[3] * inv) << 16);
      ov.z = (unsigned)f2bf(fa[4] * inv) | ((unsigned)f2bf(fa[5] * inv) << 16);
      ov.w = (unsigned)f2bf(fa[6] * inv) | ((unsigned)f2bf(fa[7] * inv) << 16);
      *(uint4*)&agg[(size_t)d * F + c32 * 8] = ov;
    }
  }
}

// ---------------- staged layer GEMM: relu(Aself@Ws + Aagg@Wn + b) L2-normalized [+ fused head] ----------------
template <int KD, bool HEAD>
__global__ __launch_bounds__(512) void layer_gemm_k(const unsigned short* __restrict__ Aself,
                                                    const unsigned short* __restrict__ Aagg,
                                                    const unsigned short* __restrict__ WtS,
                                                    const unsigned short* __restrict__ WtN,
                                                    const float* __restrict__ bias,
                                                    unsigned short* __restrict__ Hout,        // !HEAD
                                                    const unsigned short* __restrict__ Thead, // [64][256], HEAD
                                                    const float* __restrict__ bmu, const float* __restrict__ bvar,
                                                    float* __restrict__ outp, int M) {
  __shared__ unsigned short At[128][40];
  __shared__ unsigned short Bt[256][40];
  __shared__ float rowsq[4][128];
  __shared__ float rowtot[128];
  __shared__ unsigned short h2t[HEAD ? 128 : 1][HEAD ? 264 : 1];

  int tid = threadIdx.x;
  int w = tid >> 6, l = tid & 63;
  int wr = w >> 2, wc = w & 3;
  int m0 = blockIdx.x * 128;

  f32x4 acc[4][4];
#pragma unroll
  for (int rt = 0; rt < 4; ++rt)
#pragma unroll
    for (int ct = 0; ct < 4; ++ct) acc[rt][ct] = (f32x4)(0.f);

  for (int s = 0; s < 2; ++s) {
    const unsigned short* A = s ? Aagg : Aself;
    const unsigned short* Wt = s ? WtN : WtS;
    for (int k0 = 0; k0 < KD; k0 += 32) {
      {
        int r = tid >> 2, c8 = (tid & 3) << 3;
        int gr = m0 + r;
        uint4 v = make_uint4(0, 0, 0, 0);
        if (gr < M) v = *(const uint4*)&A[(size_t)gr * KD + k0 + c8];
        *(uint4*)&At[r][c8] = v;
      }
#pragma unroll
      for (int rr = 0; rr < 2; ++rr) {
        int r = (tid >> 2) + (rr << 7), c8 = (tid & 3) << 3;
        uint4 v = *(const uint4*)&Wt[(size_t)r * KD + k0 + c8];
        *(uint4*)&Bt[r][c8] = v;
      }
      __syncthreads();
      s16x8 a[4], b[4];
#pragma unroll
      for (int rt = 0; rt < 4; ++rt) a[rt] = *(const s16x8*)&At[wr * 64 + rt * 16 + (l & 15)][(l >> 4) * 8];
#pragma unroll
      for (int ct = 0; ct < 4; ++ct) b[ct] = *(const s16x8*)&Bt[wc * 64 + ct * 16 + (l & 15)][(l >> 4) * 8];
#pragma unroll
      for (int rt = 0; rt < 4; ++rt)
#pragma unroll
        for (int ct = 0; ct < 4; ++ct)
          acc[rt][ct] = __builtin_amdgcn_mfma_f32_16x16x32_bf16(a[rt], b[ct], acc[rt][ct], 0, 0, 0);
      __syncthreads();
    }
  }

  float pr[4][4];
#pragma unroll
  for (int rt = 0; rt < 4; ++rt)
#pragma unroll
    for (int j = 0; j < 4; ++j) pr[rt][j] = 0.f;
#pragma unroll
  for (int rt = 0; rt < 4; ++rt)
#pragma unroll
    for (int ct = 0; ct < 4; ++ct) {
      int c = wc * 64 + ct * 16 + (l & 15);
      float bv = bias[c];
#pragma unroll
      for (int j = 0; j < 4; ++j) {
        float vv = acc[rt][ct][j] + bv;
        vv = fmaxf(vv, 0.f);
        acc[rt][ct][j] = vv;
        pr[rt][j] += vv * vv;
      }
    }
#pragma unroll
  for (int rt = 0; rt < 4; ++rt)
#pragma unroll
    for (int j = 0; j < 4; ++j) {
      float p = pr[rt][j];
      for (int m = 1; m < 16; m <<= 1) p += __shfl_xor(p, m, 64);
      pr[rt][j] = p;
    }
  if ((l & 15) == 0) {
#pragma unroll
    for (int rt = 0; rt < 4; ++rt)
#pragma unroll
      for (int j = 0; j < 4; ++j) rowsq[wc][wr * 64 + rt * 16 + (l >> 4) * 4 + j] = pr[rt][j];
  }
  __syncthreads();
  if (tid < 128) rowtot[tid] = rowsq[0][tid] + rowsq[1][tid] + rowsq[2][tid] + rowsq[3][tid];
  __syncthreads();

  if constexpr (!HEAD) {
#pragma unroll
    for (int rt = 0; rt < 4; ++rt) {
      int rbase = wr * 64 + rt * 16 + (l >> 4) * 4;
#pragma unroll
      for (int j = 0; j < 4; ++j) {
        int r = rbase + j;
        int gr = m0 + r;
        if (gr < M) {
          float inv = 1.0f / fmaxf(sqrtf(rowtot[r]), 1e-12f);
#pragma unroll
          for (int ct = 0; ct < 4; ++ct) {
            int c = wc * 64 + ct * 16 + (l & 15);
            Hout[(size_t)gr * 256 + c] = f2bf(acc[rt][ct][j] * inv);
          }
        }
      }
    }
  } else {
#pragma unroll
    for (int rt = 0; rt < 4; ++rt) {
      int rbase = wr * 64 + rt * 16 + (l >> 4) * 4;
#pragma unroll
      for (int j = 0; j < 4; ++j) {
        int r = rbase + j;
        float inv = 1.0f / fmaxf(sqrtf(rowtot[r]), 1e-12f);
#pragma unroll
        for (int ct = 0; ct < 4; ++ct) {
          int c = wc * 64 + ct * 16 + (l & 15);
          h2t[r][c] = f2bf(acc[rt][ct][j] * inv);
        }
      }
    }
    __syncthreads();

    const int arow = wr * 64 + (l & 15);
    const int kk = (l >> 4) * 8;
    f32x4 hacc[4];
#pragma unroll
    for (int rt = 0; rt < 4; ++rt) hacc[rt] = (f32x4)(0.f);
#pragma unroll
    for (int k0 = 0; k0 < 256; k0 += 32) {
      s16x8 ha[4];
#pragma unroll
      for (int rt = 0; rt < 4; ++rt) ha[rt] = *(const s16x8*)&h2t[arow + rt * 16][k0 + kk];
      s16x8 hb = *(const s16x8*)&Thead[(size_t)(wc * 16 + (l & 15)) * 256 + k0 + kk];
#pragma unroll
      for (int rt = 0; rt < 4; ++rt)
        hacc[rt] = __builtin_amdgcn_mfma_f32_16x16x32_bf16(ha[rt], hb, hacc[rt], 0, 0, 0);
    }
    const int c = wc * 16 + (l & 15);
    const float hbias = (c < 32) ? bmu[c] : bvar[c - 32];
#pragma unroll
    for (int rt = 0; rt < 4; ++rt)
#pragma unroll
      for (int j = 0; j < 4; ++j) {
        int gr = m0 + wr * 64 + rt * 16 + (l >> 4) * 4 + j;
        if (gr < M) {
          float val = hacc[rt][j] + hbias;
          if (c < 32)
            outp[(size_t)gr * 32 + c] = val;
          else
            outp[(size_t)M * 32 + (size_t)gr * 32 + (c - 32)] = expf(val) + 1e-6f;
        }
      }
  }
}

extern "C" void kernel_launch(void* const* d_in, const int* in_sizes, int n_in,
                              void* d_out, int out_size, void* d_ws, size_t ws_size,
                              hipStream_t stream) {
  const float* x    = (const float*)d_in[0];
  const float* Ws0  = (const float*)d_in[1];
  const float* Wn0  = (const float*)d_in[2];
  const float* b0   = (const float*)d_in[3];
  const float* Ws1  = (const float*)d_in[4];
  const float* Wn1  = (const float*)d_in[5];
  const float* b1   = (const float*)d_in[6];
  const float* Wmu  = (const float*)d_in[7];
  const float* bmu  = (const float*)d_in[8];
  const float* Wvar = (const float*)d_in[9];
  const float* bvar = (const float*)d_in[10];
  const int* src0   = (const int*)d_in[11];
  const int* dst0   = (const int*)d_in[12];
  const int* src1   = (const int*)d_in[13];
  const int* dst1   = (const int*)d_in[14];

  const int N0 = in_sizes[0] / 128;  // 200000
  const int E0 = in_sizes[11];       // 800000
  const int E1 = in_sizes[13];       // 160000
  const int N1 = 50000, N2 = 10000;  // n_dst0 / n_dst1 (fixed problem shape)
  const int M = N1 + N2;

  char* ws = (char*)d_ws;
  size_t o = 0;
  auto take = [&](size_t b) -> char* {
    size_t cur = (o + 255) & ~(size_t)255;
    o = cur + b;
    return ws + cur;
  };
  unsigned short* h0    = (unsigned short*)take((size_t)(N0 + 1) * 128 * 2);  // +1 sentinel zero row
  unsigned short* agg0  = (unsigned short*)take((size_t)N1 * 128 * 2);
  unsigned short* h1    = (unsigned short*)take((size_t)(N1 + 1) * 256 * 2);  // +1 sentinel zero row
  unsigned short* agg1  = (unsigned short*)take((size_t)N2 * 256 * 2);
  unsigned short* T0s   = (unsigned short*)take(256 * 128 * 2);
  unsigned short* T0n   = (unsigned short*)take(256 * 128 * 2);
  unsigned short* T1s   = (unsigned short*)take(256 * 256 * 2);
  unsigned short* T1n   = (unsigned short*)take(256 * 256 * 2);
  unsigned short* Thead = (unsigned short*)take(64 * 256 * 2);

  int B0 = (E0 + CH - 1) / CH;   // 196
  int B1 = (E1 + CH - 1) / CH;   // 40
  int NB = B0 + B1;              // 236
  int G  = 256 * NB;
  int QB0 = (N1 + 255) / 256;    // 196
  int QB1 = (N2 + 255) / 256;    // 40
  int QF  = QB0 + QB1;           // 236

  unsigned* gh   = (unsigned*)take((size_t)G * 4);
  unsigned* off  = (unsigned*)take((size_t)M * 4);
  unsigned* cnt  = (unsigned*)take((size_t)M * 4);
  unsigned* part = (unsigned*)take(256 * 4);
  uint2* tmp = (uint2*)take((size_t)(E0 + E1) * 8);
  int* ss = (int*)take(((size_t)(E0 + E1) + (size_t)QF * PADS) * 4);  // padded CSR buffer
  (void)ws_size;

  const int n4 = N0 * 128 / 4;  // 6.4M float4
  // log1p span cut points: 8% | 8% | 9% | 35% | 40%
  const int c1 = n4 * 8 / 100, c2 = n4 * 16 / 100, c3 = n4 * 25 / 100, c4 = n4 * 60 / 100;
  const int LA = 768, LBs = 768, LC = 768;
  const int LS = 384, LF = 384;  // 1024-thread co-schedule blocks

  // 1) front: hist + weight prep + sentinel zeroing + log1p[0,c1)
  front_k<<<NB + 256 + LA, 256, 0, stream>>>(dst0, E0, dst1, E1, gh, B0, B1,
                                             Ws0, Wn0, Ws1, Wn1, Wmu, Wvar,
                                             T0s, T0n, T1s, T1n, Thead,
                                             h1, N0, N1,
                                             x, h0, 0, c1, LA);

  // 2) scan sums + log1p[c1,c2) ; scan write + log1p[c2,c3)
  scan_sums_k<<<NB + LBs, 256, 0, stream>>>(gh, NB, part, x, h0, c1, c2, LBs);
  scan_write_k<<<NB + LC, 256, 0, stream>>>(gh, NB, part, x, h0, c2, c3, LC);

  // 3) scatter (1024 thr) + log1p[c3,c4) ; finalize (1024 thr, padded) + log1p[c4,n4)
  scatter2_k<<<NB + LS, 1024, 0, stream>>>(src0, dst0, E0, src1, dst1, E1, gh, B0, B1, tmp,
                                           x, h0, c3, c4, LS);
  finalize_k<<<QF + LF, 1024, 0, stream>>>(tmp, gh, B0, B1, N1, N2, off, cnt, ss, QB0, QB1,
                                           N0, N1,
                                           x, h0, c4, n4, LF);

  // 4) layer 0: aggregate (uniform padded batches) then staged GEMM -> h1
  aggregate_k<128><<<(N1 + 3) / 4, 256, 0, stream>>>(h0, ss, off, cnt, agg0, N1);
  layer_gemm_k<128, false><<<(N1 + 127) / 128, 512, 0, stream>>>(h0, agg0, T0s, T0n, b0,
                                                                 h1, nullptr, nullptr, nullptr, nullptr, N1);

  // 5) layer 1: aggregate then staged GEMM + fused head -> out
  aggregate_k<256><<<(N2 + 3) / 4, 256, 0, stream>>>(h1, ss, off + N1, cnt + N1, agg1, N2);
  layer_gemm_k<256, true><<<(N2 + 127) / 128, 512, 0, stream>>>(h1, agg1, T1s, T1n, b1,
                                                                nullptr, Thead, bmu, bvar, (float*)d_out, N2);
}

// Round 16
// 148.637 us; speedup vs baseline: 1.1426x; 1.0085x over previous
//
#include <hip/hip_runtime.h>
#include <math.h>

#define DEVI static __device__ __forceinline__

typedef __attribute__((ext_vector_type(8))) short s16x8;
typedef __attribute__((ext_vector_type(4))) float f32x4;

constexpr int CH = 4096;    // edges per partition block in CSR build
constexpr int PADS = 3840;  // per-bucket pad slack: 256 dst * <=15 pad each

DEVI float bf2f(unsigned short u) {
  union { unsigned int i; float f; } v; v.i = ((unsigned int)u) << 16; return v.f;
}
DEVI unsigned short f2bf(float f) {
  union { float f; unsigned int i; } v; v.f = f;
  return (unsigned short)((v.i + 0x7fffu + ((v.i >> 16) & 1u)) >> 16);
}

// fast log1p for x in [0,1): 1+x in [1,2), no cancellation; hw log2 + scale.
DEVI float fast_log1p(float x) {
  float t = x + 1.0f;
  float l;
  asm("v_log_f32 %0, %1" : "=v"(l) : "v"(t));
  return l * 0.6931471805599453f;
}

// works for any blockDim.x (256 or 1024 callers)
DEVI void log1p_span(const float* __restrict__ x, unsigned short* __restrict__ h0,
                     int lo, int hi, int blk, int nblk) {
  int bs = blockDim.x;
  int stride = nblk * bs;
  for (int i = lo + blk * bs + threadIdx.x; i < hi; i += stride) {
    float4 v = ((const float4*)x)[i];
    ushort4 o;
    o.x = f2bf(fast_log1p(v.x)); o.y = f2bf(fast_log1p(v.y));
    o.z = f2bf(fast_log1p(v.z)); o.w = f2bf(fast_log1p(v.w));
    ((ushort4*)h0)[i] = o;
  }
}

// ---------------- front: hist (CSR level-1a) | weight prep + sentinel zeroing | log1p span ----------------
__global__ __launch_bounds__(256) void front_k(const int* __restrict__ dst0, int E0,
                                               const int* __restrict__ dst1, int E1,
                                               unsigned* __restrict__ gh, int B0, int B1,
                                               const float* __restrict__ Ws0, const float* __restrict__ Wn0,
                                               const float* __restrict__ Ws1, const float* __restrict__ Wn1,
                                               const float* __restrict__ Wmu, const float* __restrict__ Wvar,
                                               unsigned short* __restrict__ T0s, unsigned short* __restrict__ T0n,
                                               unsigned short* __restrict__ T1s, unsigned short* __restrict__ T1n,
                                               unsigned short* __restrict__ Thead,
                                               unsigned short* __restrict__ h1z, int N0, int N1,
                                               const float* __restrict__ x, unsigned short* __restrict__ h0,
                                               int lo, int hi, int LA) {
  __shared__ unsigned h[256];
  int b = blockIdx.x;
  int t = threadIdx.x;
  int BH = B0 + B1;
  if (b < BH) {
    bool L1 = b >= B0;
    const int* dst = L1 ? dst1 : dst0;
    int E = L1 ? E1 : E0;
    int base = L1 ? b - B0 : b;
    unsigned* out = L1 ? gh + 256 * B0 : gh;
    int B = L1 ? B1 : B0;
    h[t] = 0;
    __syncthreads();
    int e0 = base * CH, eend = min(e0 + CH, E);
    for (int i = e0 + t; i < eend; i += 256) atomicAdd(&h[((unsigned)dst[i]) >> 8], 1u);
    __syncthreads();
    out[t * B + base] = h[t];
  } else if (b < BH + 256) {
    if (b == BH) {  // zero the sentinel rows (gather targets for pad edges)
      if (t < 64) ((unsigned*)h0)[(size_t)N0 * 64 + t] = 0u;    // h0 row N0 (128 bf16)
      if (t < 128) ((unsigned*)h1z)[(size_t)N1 * 128 + t] = 0u; // h1 row N1 (256 bf16)
    }
    int i = (b - BH) * 256 + t;
    if (i < 32768) {  // [256][128]
      int hh = i >> 7, k = i & 127;
      T0s[i] = f2bf(Ws0[k * 256 + hh]);
      T0n[i] = f2bf(Wn0[k * 256 + hh]);
    }
    if (i < 65536) {  // [256][256]
      int hh = i >> 8, k = i & 255;
      T1s[i] = f2bf(Ws1[k * 256 + hh]);
      T1n[i] = f2bf(Wn1[k * 256 + hh]);
    }
    if (i < 16384) {  // Thead[64][256]
      int c = i >> 8, k = i & 255;
      Thead[i] = f2bf(c < 32 ? Wmu[k * 32 + c] : Wvar[k * 32 + (c - 32)]);
    }
  } else {
    log1p_span(x, h0, lo, hi, b - BH - 256, LA);
  }
}

// ---------------- scan: per-chunk sums | log1p span ----------------
__global__ __launch_bounds__(256) void scan_sums_k(const unsigned* __restrict__ a, int NB,
                                                   unsigned* __restrict__ part,
                                                   const float* __restrict__ x, unsigned short* __restrict__ h0,
                                                   int lo, int hi, int LB) {
  __shared__ unsigned sm[256];
  int b = blockIdx.x, t = threadIdx.x;
  if (b >= NB) { log1p_span(x, h0, lo, hi, b - NB, LB); return; }
  sm[t] = a[b * 256 + t];
  __syncthreads();
  for (int o = 128; o > 0; o >>= 1) {
    if (t < o) sm[t] += sm[t + o];
    __syncthreads();
  }
  if (t == 0) part[b] = sm[0];
}

// ---------------- scan: self-service partial scan + chunk exclusive scan + write | log1p span ----------------
__global__ __launch_bounds__(256) void scan_write_k(unsigned* __restrict__ a, int NB,
                                                    const unsigned* __restrict__ part,
                                                    const float* __restrict__ x, unsigned short* __restrict__ h0,
                                                    int lo, int hi, int LC) {
  __shared__ unsigned sm[256];
  int b = blockIdx.x, t = threadIdx.x;
  if (b >= NB) { log1p_span(x, h0, lo, hi, b - NB, LC); return; }
  unsigned pv = (t < NB) ? part[t] : 0u;
  sm[t] = pv;
  __syncthreads();
  for (int o = 1; o < 256; o <<= 1) {
    unsigned xv = (t >= o) ? sm[t - o] : 0u;
    __syncthreads();
    sm[t] += xv;
    __syncthreads();
  }
  unsigned pb = (b == 0) ? 0u : sm[b - 1];
  __syncthreads();
  unsigned v = a[b * 256 + t];
  sm[t] = v;
  __syncthreads();
  for (int o = 1; o < 256; o <<= 1) {
    unsigned xv = (t >= o) ? sm[t - o] : 0u;
    __syncthreads();
    sm[t] += xv;
    __syncthreads();
  }
  a[b * 256 + t] = pb + sm[t] - v;
}

// ---------------- scatter: 1024-thread blocks (16 waves/CU, 4x edge TLP) (+ log1p span) ----------------
__global__ __launch_bounds__(1024) void scatter2_k(const int* __restrict__ src0, const int* __restrict__ dst0, int E0,
                                                   const int* __restrict__ src1, const int* __restrict__ dst1, int E1,
                                                   const unsigned* __restrict__ gh, int B0, int B1,
                                                   uint2* __restrict__ tmp,
                                                   const float* __restrict__ x, unsigned short* __restrict__ h0,
                                                   int lo, int hi, int LS) {
  __shared__ unsigned cur[256];
  int b = blockIdx.x;
  int NB = B0 + B1;
  if (b >= NB) { log1p_span(x, h0, lo, hi, b - NB, LS); return; }
  bool L1 = b >= B0;
  const int* dst = L1 ? dst1 : dst0;
  const int* src = L1 ? src1 : src0;
  int E = L1 ? E1 : E0;
  int base = L1 ? b - B0 : b;
  const unsigned* g = L1 ? gh + 256 * B0 : gh;
  int B = L1 ? B1 : B0;
  int t = threadIdx.x;
  if (t < 256) cur[t] = g[t * B + base];
  __syncthreads();
  int e0 = base * CH, eend = min(e0 + CH, E);
  for (int i = e0 + t; i < eend; i += 1024) {
    int d = dst[i];
    unsigned p = atomicAdd(&cur[((unsigned)d) >> 8], 1u);
    tmp[p] = make_uint2((unsigned)d, (unsigned)src[i]);
  }
}

// ---------------- finalize: 1024-thread blocks, padded segments + sentinel fill (+ log1p span) ----------------
__global__ __launch_bounds__(1024) void finalize_k(const uint2* __restrict__ tmp, const unsigned* __restrict__ gh,
                                                   int B0, int B1, int N1, int N2,
                                                   unsigned* __restrict__ off, unsigned* __restrict__ cnt,
                                                   int* __restrict__ ss, int QB0, int QB1,
                                                   int sent0, int sent1,
                                                   const float* __restrict__ x, unsigned short* __restrict__ h0,
                                                   int lo, int hi, int LF) {
  __shared__ unsigned h[256];
  __shared__ unsigned sm[256];
  __shared__ unsigned co[256];
  int q = blockIdx.x;
  int QF = QB0 + QB1;
  if (q >= QF) { log1p_span(x, h0, lo, hi, q - QF, LF); return; }
  bool L1 = q >= QB0;
  int Nd = L1 ? N2 : N1;
  int qb = L1 ? q - QB0 : q;
  const unsigned* g = L1 ? gh + 256 * B0 : gh;
  int B = L1 ? B1 : B0;
  int t = threadIdx.x;
  unsigned bstart = g[qb * B];
  unsigned bend = g[(qb + 1) * B];
  unsigned nbk = bend - bstart;
  unsigned pbase = bstart + (unsigned)q * PADS;  // per-bucket padded region start

  if (t < 256) h[t] = 0;
  __syncthreads();
  for (unsigned i = t; i < nbk; i += 1024) atomicAdd(&h[tmp[bstart + i].x & 255u], 1u);
  __syncthreads();
  unsigned v = 0, vpad = 0;
  if (t < 256) {
    v = h[t];
    vpad = (v + 15u) & ~15u;
    sm[t] = vpad;
  }
  __syncthreads();
  for (int o = 1; o < 256; o <<= 1) {
    unsigned xv = 0;
    if (t < 256 && t >= o) xv = sm[t - o];
    __syncthreads();
    if (t < 256) sm[t] += xv;
    __syncthreads();
  }
  if (t < 256) {
    unsigned myoff = pbase + sm[t] - vpad;
    int dl = qb * 256 + t;
    if (dl < Nd) {
      int dg = (L1 ? N1 : 0) + dl;
      off[dg] = myoff;
      cnt[dg] = v;  // TRUE degree for the mean
    }
    co[t] = myoff;
    // pad fill: disjoint region per dst
    int sent = L1 ? sent1 : sent0;
    for (unsigned j = v; j < vpad; ++j) ss[myoff + j] = sent;
  }
  __syncthreads();
  for (unsigned i = t; i < nbk; i += 1024) {
    uint2 e = tmp[bstart + i];
    unsigned p = atomicAdd(&co[e.x & 255u], 1u);
    ss[p] = (int)e.y;
  }
}

// ---------------- mean aggregation ----------------
// F=128 quarter-wave: 16 lanes x uint4 per row, 4 edges concurrent, 32 edges per main step.
template <int UL>
DEVI void gstepQ(const unsigned short* __restrict__ hsrc, const int* __restrict__ ss,
                 unsigned base, int q, int c16, float* fa) {
  int sv[UL];
#pragma unroll
  for (int u = 0; u < UL; ++u) sv[u] = ss[base + 4 * u + q];
  uint4 v[UL];
#pragma unroll
  for (int u = 0; u < UL; ++u) v[u] = *(const uint4*)&hsrc[(size_t)sv[u] * 128 + c16 * 8];
#pragma unroll
  for (int u = 0; u < UL; ++u) {
    fa[0] += bf2f((unsigned short)(v[u].x & 0xffffu));
    fa[1] += bf2f((unsigned short)(v[u].x >> 16));
    fa[2] += bf2f((unsigned short)(v[u].y & 0xffffu));
    fa[3] += bf2f((unsigned short)(v[u].y >> 16));
    fa[4] += bf2f((unsigned short)(v[u].z & 0xffffu));
    fa[5] += bf2f((unsigned short)(v[u].z >> 16));
    fa[6] += bf2f((unsigned short)(v[u].w & 0xffffu));
    fa[7] += bf2f((unsigned short)(v[u].w >> 16));
  }
}

// F=256 half-wave: 32 lanes x uint4 per row, 2 edges concurrent, 16 edges per step.
template <int UL>
DEVI void gstepH(const unsigned short* __restrict__ hsrc, const int* __restrict__ ss,
                 unsigned base, int half, int c32, float* fa) {
  int sv[UL];
#pragma unroll
  for (int u = 0; u < UL; ++u) sv[u] = ss[base + 2 * u + half];
  uint4 v[UL];
#pragma unroll
  for (int u = 0; u < UL; ++u) v[u] = *(const uint4*)&hsrc[(size_t)sv[u] * 256 + c32 * 8];
#pragma unroll
  for (int u = 0; u < UL; ++u) {
    fa[0] += bf2f((unsigned short)(v[u].x & 0xffffu));
    fa[1] += bf2f((unsigned short)(v[u].x >> 16));
    fa[2] += bf2f((unsigned short)(v[u].y & 0xffffu));
    fa[3] += bf2f((unsigned short)(v[u].y >> 16));
    fa[4] += bf2f((unsigned short)(v[u].z & 0xffffu));
    fa[5] += bf2f((unsigned short)(v[u].z >> 16));
    fa[6] += bf2f((unsigned short)(v[u].w & 0xffffu));
    fa[7] += bf2f((unsigned short)(v[u].w >> 16));
  }
}

template <int F>  // 128 or 256
__global__ __launch_bounds__(256) void aggregate_k(const unsigned short* __restrict__ hsrc,
                                                   const int* __restrict__ ss,
                                                   const unsigned* __restrict__ off,
                                                   const unsigned* __restrict__ cnt,
                                                   unsigned short* __restrict__ agg, int M) {
  int w = threadIdx.x >> 6, l = threadIdx.x & 63;
  int d = blockIdx.x * 4 + w;
  if (d >= M) return;
  unsigned o = off[d];
  int n = (int)cnt[d];
  int npad = (n + 15) & ~15;  // segments pre-padded with sentinel (zero-row) edges
  float inv = 1.0f / (float)((n > 0) ? n : 1);

  if constexpr (F == 128) {
    int q = l >> 4, c16 = l & 15;
    float fa[8];
#pragma unroll
    for (int f = 0; f < 8; ++f) fa[f] = 0.f;
    int i = 0;
    for (; i + 32 <= npad; i += 32) gstepQ<8>(hsrc, ss, o + i, q, c16, fa);  // 32 edges, 128B/lane in flight
    if (i < npad) gstepQ<4>(hsrc, ss, o + i, q, c16, fa);                    // remaining 16
#pragma unroll
    for (int f = 0; f < 8; ++f) {
      fa[f] += __shfl_xor(fa[f], 16, 64);
      fa[f] += __shfl_xor(fa[f], 32, 64);
    }
    if (l < 16) {
      uint4 ov;
      ov.x = (unsigned)f2bf(fa[0] * inv) | ((unsigned)f2bf(fa[1] * inv) << 16);
      ov.y = (unsigned)f2bf(fa[2] * inv) | ((unsigned)f2bf(fa[3] * inv) << 16);
      ov.z = (unsigned)f2bf(fa[4] * inv) | ((unsigned)f2bf(fa[5] * inv) << 16);
      ov.w = (unsigned)f2bf(fa[6] * inv) | ((unsigned)f2bf(fa[7] * inv) << 16);
      *(uint4*)&agg[(size_t)d * 128 + c16 * 8] = ov;
    }
  } else {
    int half = l >> 5, c32 = l & 31;
    float fa[8];
#pragma unroll
    for (int f = 0; f < 8; ++f) fa[f] = 0.f;
    for (int i = 0; i < npad; i += 16) gstepH<8>(hsrc, ss, o + i, half, c32, fa);
#pragma unroll
    for (int f = 0; f < 8; ++f) fa[f] += __shfl_xor(fa[f], 32, 64);
    if (l < 32) {
      uint4 ov;
      ov.x = (unsigned)f2bf(fa[0] * inv) | ((unsigned)f2bf(fa[1] * inv) << 16);
      ov.y = (unsigned)f2bf(fa[2] * inv) | ((unsigned)f2bf(fa[3] * inv) << 16);
      ov.z = (unsigned)f2bf(fa[4] * inv) | ((unsigned)f2bf(fa[5] * inv) << 16);
      ov.w = (unsigned)f2bf(fa[6] * inv) | ((unsigned)f2bf(fa[7] * inv) << 16);
      *(uint4*)&agg[(size_t)d * 256 + c32 * 8] = ov;
    }
  }
}

// ---------------- staged layer GEMM: relu(Aself@Ws + Aagg@Wn + b) L2-normalized [+ fused head] ----------------
template <int KD, bool HEAD>
__global__ __launch_bounds__(512) void layer_gemm_k(const unsigned short* __restrict__ Aself,
                                                    const unsigned short* __restrict__ Aagg,
                                                    const unsigned short* __restrict__ WtS,
                                                    const unsigned short* __restrict__ WtN,
                                                    const float* __restrict__ bias,
                                                    unsigned short* __restrict__ Hout,        // !HEAD
                                                    const unsigned short* __restrict__ Thead, // [64][256], HEAD
                                                    const float* __restrict__ bmu, const float* __restrict__ bvar,
                                                    float* __restrict__ outp, int M) {
  __shared__ unsigned short At[128][40];
  __shared__ unsigned short Bt[256][40];
  __shared__ float rowsq[4][128];
  __shared__ float rowtot[128];
  __shared__ unsigned short h2t[HEAD ? 128 : 1][HEAD ? 264 : 1];

  int tid = threadIdx.x;
  int w = tid >> 6, l = tid & 63;
  int wr = w >> 2, wc = w & 3;
  int m0 = blockIdx.x * 128;

  f32x4 acc[4][4];
#pragma unroll
  for (int rt = 0; rt < 4; ++rt)
#pragma unroll
    for (int ct = 0; ct < 4; ++ct) acc[rt][ct] = (f32x4)(0.f);

  for (int s = 0; s < 2; ++s) {
    const unsigned short* A = s ? Aagg : Aself;
    const unsigned short* Wt = s ? WtN : WtS;
    for (int k0 = 0; k0 < KD; k0 += 32) {
      {
        int r = tid >> 2, c8 = (tid & 3) << 3;
        int gr = m0 + r;
        uint4 v = make_uint4(0, 0, 0, 0);
        if (gr < M) v = *(const uint4*)&A[(size_t)gr * KD + k0 + c8];
        *(uint4*)&At[r][c8] = v;
      }
#pragma unroll
      for (int rr = 0; rr < 2; ++rr) {
        int r = (tid >> 2) + (rr << 7), c8 = (tid & 3) << 3;
        uint4 v = *(const uint4*)&Wt[(size_t)r * KD + k0 + c8];
        *(uint4*)&Bt[r][c8] = v;
      }
      __syncthreads();
      s16x8 a[4], b[4];
#pragma unroll
      for (int rt = 0; rt < 4; ++rt) a[rt] = *(const s16x8*)&At[wr * 64 + rt * 16 + (l & 15)][(l >> 4) * 8];
#pragma unroll
      for (int ct = 0; ct < 4; ++ct) b[ct] = *(const s16x8*)&Bt[wc * 64 + ct * 16 + (l & 15)][(l >> 4) * 8];
#pragma unroll
      for (int rt = 0; rt < 4; ++rt)
#pragma unroll
        for (int ct = 0; ct < 4; ++ct)
          acc[rt][ct] = __builtin_amdgcn_mfma_f32_16x16x32_bf16(a[rt], b[ct], acc[rt][ct], 0, 0, 0);
      __syncthreads();
    }
  }

  float pr[4][4];
#pragma unroll
  for (int rt = 0; rt < 4; ++rt)
#pragma unroll
    for (int j = 0; j < 4; ++j) pr[rt][j] = 0.f;
#pragma unroll
  for (int rt = 0; rt < 4; ++rt)
#pragma unroll
    for (int ct = 0; ct < 4; ++ct) {
      int c = wc * 64 + ct * 16 + (l & 15);
      float bv = bias[c];
#pragma unroll
      for (int j = 0; j < 4; ++j) {
        float vv = acc[rt][ct][j] + bv;
        vv = fmaxf(vv, 0.f);
        acc[rt][ct][j] = vv;
        pr[rt][j] += vv * vv;
      }
    }
#pragma unroll
  for (int rt = 0; rt < 4; ++rt)
#pragma unroll
    for (int j = 0; j < 4; ++j) {
      float p = pr[rt][j];
      for (int m = 1; m < 16; m <<= 1) p += __shfl_xor(p, m, 64);
      pr[rt][j] = p;
    }
  if ((l & 15) == 0) {
#pragma unroll
    for (int rt = 0; rt < 4; ++rt)
#pragma unroll
      for (int j = 0; j < 4; ++j) rowsq[wc][wr * 64 + rt * 16 + (l >> 4) * 4 + j] = pr[rt][j];
  }
  __syncthreads();
  if (tid < 128) rowtot[tid] = rowsq[0][tid] + rowsq[1][tid] + rowsq[2][tid] + rowsq[3][tid];
  __syncthreads();

  if constexpr (!HEAD) {
#pragma unroll
    for (int rt = 0; rt < 4; ++rt) {
      int rbase = wr * 64 + rt * 16 + (l >> 4) * 4;
#pragma unroll
      for (int j = 0; j < 4; ++j) {
        int r = rbase + j;
        int gr = m0 + r;
        if (gr < M) {
          float inv = 1.0f / fmaxf(sqrtf(rowtot[r]), 1e-12f);
#pragma unroll
          for (int ct = 0; ct < 4; ++ct) {
            int c = wc * 64 + ct * 16 + (l & 15);
            Hout[(size_t)gr * 256 + c] = f2bf(acc[rt][ct][j] * inv);
          }
        }
      }
    }
  } else {
#pragma unroll
    for (int rt = 0; rt < 4; ++rt) {
      int rbase = wr * 64 + rt * 16 + (l >> 4) * 4;
#pragma unroll
      for (int j = 0; j < 4; ++j) {
        int r = rbase + j;
        float inv = 1.0f / fmaxf(sqrtf(rowtot[r]), 1e-12f);
#pragma unroll
        for (int ct = 0; ct < 4; ++ct) {
          int c = wc * 64 + ct * 16 + (l & 15);
          h2t[r][c] = f2bf(acc[rt][ct][j] * inv);
        }
      }
    }
    __syncthreads();

    const int arow = wr * 64 + (l & 15);
    const int kk = (l >> 4) * 8;
    f32x4 hacc[4];
#pragma unroll
    for (int rt = 0; rt < 4; ++rt) hacc[rt] = (f32x4)(0.f);
#pragma unroll
    for (int k0 = 0; k0 < 256; k0 += 32) {
      s16x8 ha[4];
#pragma unroll
      for (int rt = 0; rt < 4; ++rt) ha[rt] = *(const s16x8*)&h2t[arow + rt * 16][k0 + kk];
      s16x8 hb = *(const s16x8*)&Thead[(size_t)(wc * 16 + (l & 15)) * 256 + k0 + kk];
#pragma unroll
      for (int rt = 0; rt < 4; ++rt)
        hacc[rt] = __builtin_amdgcn_mfma_f32_16x16x32_bf16(ha[rt], hb, hacc[rt], 0, 0, 0);
    }
    const int c = wc * 16 + (l & 15);
    const float hbias = (c < 32) ? bmu[c] : bvar[c - 32];
#pragma unroll
    for (int rt = 0; rt < 4; ++rt)
#pragma unroll
      for (int j = 0; j < 4; ++j) {
        int gr = m0 + wr * 64 + rt * 16 + (l >> 4) * 4 + j;
        if (gr < M) {
          float val = hacc[rt][j] + hbias;
          if (c < 32)
            outp[(size_t)gr * 32 + c] = val;
          else
            outp[(size_t)M * 32 + (size_t)gr * 32 + (c - 32)] = expf(val) + 1e-6f;
        }
      }
  }
}

extern "C" void kernel_launch(void* const* d_in, const int* in_sizes, int n_in,
                              void* d_out, int out_size, void* d_ws, size_t ws_size,
                              hipStream_t stream) {
  const float* x    = (const float*)d_in[0];
  const float* Ws0  = (const float*)d_in[1];
  const float* Wn0  = (const float*)d_in[2];
  const float* b0   = (const float*)d_in[3];
  const float* Ws1  = (const float*)d_in[4];
  const float* Wn1  = (const float*)d_in[5];
  const float* b1   = (const float*)d_in[6];
  const float* Wmu  = (const float*)d_in[7];
  const float* bmu  = (const float*)d_in[8];
  const float* Wvar = (const float*)d_in[9];
  const float* bvar = (const float*)d_in[10];
  const int* src0   = (const int*)d_in[11];
  const int* dst0   = (const int*)d_in[12];
  const int* src1   = (const int*)d_in[13];
  const int* dst1   = (const int*)d_in[14];

  const int N0 = in_sizes[0] / 128;  // 200000
  const int E0 = in_sizes[11];       // 800000
  const int E1 = in_sizes[13];       // 160000
  const int N1 = 50000, N2 = 10000;  // n_dst0 / n_dst1 (fixed problem shape)
  const int M = N1 + N2;

  char* ws = (char*)d_ws;
  size_t o = 0;
  auto take = [&](size_t b) -> char* {
    size_t cur = (o + 255) & ~(size_t)255;
    o = cur + b;
    return ws + cur;
  };
  unsigned short* h0    = (unsigned short*)take((size_t)(N0 + 1) * 128 * 2);  // +1 sentinel zero row
  unsigned short* agg0  = (unsigned short*)take((size_t)N1 * 128 * 2);
  unsigned short* h1    = (unsigned short*)take((size_t)(N1 + 1) * 256 * 2);  // +1 sentinel zero row
  unsigned short* agg1  = (unsigned short*)take((size_t)N2 * 256 * 2);
  unsigned short* T0s   = (unsigned short*)take(256 * 128 * 2);
  unsigned short* T0n   = (unsigned short*)take(256 * 128 * 2);
  unsigned short* T1s   = (unsigned short*)take(256 * 256 * 2);
  unsigned short* T1n   = (unsigned short*)take(256 * 256 * 2);
  unsigned short* Thead = (unsigned short*)take(64 * 256 * 2);

  int B0 = (E0 + CH - 1) / CH;   // 196
  int B1 = (E1 + CH - 1) / CH;   // 40
  int NB = B0 + B1;              // 236
  int G  = 256 * NB;
  int QB0 = (N1 + 255) / 256;    // 196
  int QB1 = (N2 + 255) / 256;    // 40
  int QF  = QB0 + QB1;           // 236

  unsigned* gh   = (unsigned*)take((size_t)G * 4);
  unsigned* off  = (unsigned*)take((size_t)M * 4);
  unsigned* cnt  = (unsigned*)take((size_t)M * 4);
  unsigned* part = (unsigned*)take(256 * 4);
  uint2* tmp = (uint2*)take((size_t)(E0 + E1) * 8);
  int* ss = (int*)take(((size_t)(E0 + E1) + (size_t)QF * PADS) * 4);  // padded CSR buffer
  (void)ws_size;

  const int n4 = N0 * 128 / 4;  // 6.4M float4
  // log1p span cut points: 8% | 8% | 9% | 35% | 40%
  const int c1 = n4 * 8 / 100, c2 = n4 * 16 / 100, c3 = n4 * 25 / 100, c4 = n4 * 60 / 100;
  const int LA = 768, LBs = 768, LC = 768;
  const int LS = 384, LF = 384;  // 1024-thread co-schedule blocks

  // 1) front: hist + weight prep + sentinel zeroing + log1p[0,c1)
  front_k<<<NB + 256 + LA, 256, 0, stream>>>(dst0, E0, dst1, E1, gh, B0, B1,
                                             Ws0, Wn0, Ws1, Wn1, Wmu, Wvar,
                                             T0s, T0n, T1s, T1n, Thead,
                                             h1, N0, N1,
                                             x, h0, 0, c1, LA);

  // 2) scan sums + log1p[c1,c2) ; scan write + log1p[c2,c3)
  scan_sums_k<<<NB + LBs, 256, 0, stream>>>(gh, NB, part, x, h0, c1, c2, LBs);
  scan_write_k<<<NB + LC, 256, 0, stream>>>(gh, NB, part, x, h0, c2, c3, LC);

  // 3) scatter (1024 thr) + log1p[c3,c4) ; finalize (1024 thr, padded) + log1p[c4,n4)
  scatter2_k<<<NB + LS, 1024, 0, stream>>>(src0, dst0, E0, src1, dst1, E1, gh, B0, B1, tmp,
                                           x, h0, c3, c4, LS);
  finalize_k<<<QF + LF, 1024, 0, stream>>>(tmp, gh, B0, B1, N1, N2, off, cnt, ss, QB0, QB1,
                                           N0, N1,
                                           x, h0, c4, n4, LF);

  // 4) layer 0: aggregate (quarter-wave uint4 gathers) then staged GEMM -> h1
  aggregate_k<128><<<(N1 + 3) / 4, 256, 0, stream>>>(h0, ss, off, cnt, agg0, N1);
  layer_gemm_k<128, false><<<(N1 + 127) / 128, 512, 0, stream>>>(h0, agg0, T0s, T0n, b0,
                                                                 h1, nullptr, nullptr, nullptr, nullptr, N1);

  // 5) layer 1: aggregate then staged GEMM + fused head -> out
  aggregate_k<256><<<(N2 + 3) / 4, 256, 0, stream>>>(h1, ss, off + N1, cnt + N1, agg1, N2);
  layer_gemm_k<256, true><<<(N2 + 127) / 128, 512, 0, stream>>>(h1, agg1, T1s, T1n, b1,
                                                                nullptr, Thead, bmu, bvar, (float*)d_out, N2);
}